// Round 11
// baseline (4113.386 us; speedup 1.0000x reference)
//
#include <hip/hip_runtime.h>
#include <hip/hip_bf16.h>

typedef short s8v __attribute__((ext_vector_type(8)));
typedef float f4v __attribute__((ext_vector_type(4)));
typedef unsigned int u4v __attribute__((ext_vector_type(4)));
typedef unsigned int u2v __attribute__((ext_vector_type(2)));

#define NBLK 64
#define TPB 512

constexpr int BB = 32, TT = 512, DD = 512, HH = 1024;
constexpr int KK = DD + HH;          // 1536
constexpr int PK = KK + 8;           // padded LDS K-stride
constexpr int PK8 = PK / 8;
constexpr int K8 = KK / 8;

// ---- workspace layout (bytes) ----
constexpr size_t OFF_WGT = 0;
constexpr size_t SZ_WGT  = (size_t)2 * HH * KK * 2;
constexpr size_t OFF_WCT = OFF_WGT + SZ_WGT;
constexpr size_t SZ_WCT  = (size_t)HH * KK * 2;
constexpr size_t OFF_XBF = OFF_WCT + SZ_WCT;
constexpr size_t SZ_XBF  = (size_t)BB * TT * DD * 2;
constexpr size_t OFF_HPB = OFF_XBF + SZ_XBF;                    // h publish (coherent)
constexpr size_t SZ_PUB  = (size_t)BB * HH * 2;
constexpr size_t OFF_RPB = OFF_HPB + SZ_PUB;                    // rh publish (coherent)
constexpr size_t OFF_FLG = OFF_RPB + SZ_PUB;                    // 2 arrays x [64 blk][2 rt][4 q] ints
constexpr size_t SZ_FLG  = (size_t)2 * NBLK * 8 * 4;            // 4,096

// ---------------------------------------------------------------------------
__global__ void wtr_kernel(const float* __restrict__ in, unsigned short* __restrict__ out, int N) {
    __shared__ float tl[32][33];
    int tx = threadIdx.x & 31, ty = threadIdx.x >> 5;
    int n0 = blockIdx.x * 32, k0 = blockIdx.y * 32;
#pragma unroll
    for (int r = ty; r < 32; r += 8) tl[r][tx] = in[(size_t)(k0 + r) * N + n0 + tx];
    __syncthreads();
#pragma unroll
    for (int r = ty; r < 32; r += 8) {
        __hip_bfloat16 h = __float2bfloat16(tl[tx][r]);
        out[(size_t)(n0 + r) * KK + k0 + tx] = *reinterpret_cast<unsigned short*>(&h);
    }
}

__global__ void xconv_kernel(const float* __restrict__ X, unsigned short* __restrict__ Xbf) {
    size_t i = ((size_t)blockIdx.x * 256 + threadIdx.x) * 4;
    float4 v = *reinterpret_cast<const float4*>(X + i);
    __hip_bfloat16 h0 = __float2bfloat16(v.x), h1 = __float2bfloat16(v.y);
    __hip_bfloat16 h2 = __float2bfloat16(v.z), h3 = __float2bfloat16(v.w);
    ushort4 o;
    o.x = *(unsigned short*)&h0; o.y = *(unsigned short*)&h1;
    o.z = *(unsigned short*)&h2; o.w = *(unsigned short*)&h3;
    *reinterpret_cast<ushort4*>(Xbf + i) = o;
}

// ---------------------------------------------------------------------------
// Proven coherent primitives (r2-r10): sc0 sc1 (system scope) loads/stores for
// all cross-block data and flags. No fences, no other cache-scope tricks.
__device__ __forceinline__ u4v cload16(const void* p) {
    u4v r; asm volatile("global_load_dwordx4 %0, %1, off sc0 sc1" : "=v"(r) : "v"(p) : "memory"); return r;
}
__device__ __forceinline__ void cstore8(void* p, u2v v) {
    asm volatile("global_store_dwordx2 %0, %1, off sc0 sc1" :: "v"(p), "v"(v) : "memory");
}
__device__ __forceinline__ void cstore4(void* p, int v) {
    asm volatile("global_store_dword %0, %1, off sc0 sc1" :: "v"(p), "v"(v) : "memory");
}
#define B16(x) __builtin_bit_cast(s8v, (x))
#define WAIT_VM(n) do { asm volatile("s_waitcnt vmcnt(" #n ")" ::: "memory"); \
                        __builtin_amdgcn_sched_barrier(0); } while (0)

// Consumer poll: 16 lanes each watch one producer block's 4 quad-flags (one
// dwordx4). Flags are monotonic generations; dword tearing is impossible.
__device__ __forceinline__ void pollq(const int* flags, int blk0, int rtw, int gen, int lane) {
    if (lane < 16) {
        const int* fp = flags + (size_t)(blk0 + lane) * 8 + rtw * 4;
        while (true) {
            u4v f; asm volatile("global_load_dwordx4 %0, %1, off sc0 sc1\ns_waitcnt vmcnt(0)"
                                : "=v"(f) : "v"(fp) : "memory");
            if ((int)f[0] >= gen && (int)f[1] >= gen && (int)f[2] >= gen && (int)f[3] >= gen) break;
            __builtin_amdgcn_s_sleep(1);
        }
    }
    asm volatile("" ::: "memory");     // keep subsequent loads below the poll
}

#define MFMA(A, B, C) __builtin_amdgcn_mfma_f32_16x16x32_bf16((A), (B), (C), 0, 0, 0)

__device__ __forceinline__ float bfu2f(unsigned short u) {
    unsigned int w = (unsigned int)u << 16;
    return __builtin_bit_cast(float, w);
}

// ---------------------------------------------------------------------------
// Persistent kernel, 64 blocks x 512 threads (8 waves), 1 block/CU.
// Block b owns r/u/cand columns [b*16, b*16+16).
// Waves: ks = wid>>1 (4-way K-split AND finalize-quad), rt = wid&1 (row tile).
// Each wave finalizes/publishes rows [rt*16+ks*4, +4) (1 value per lane);
// hprev/u are per-lane scalars. r-gate is computed first (critical path);
// u-gate + candidate-x fill the slack before the rh poll.
__global__ __launch_bounds__(TPB, 1) void gru_kernel(
    const unsigned short* __restrict__ Xbf,
    const unsigned short* __restrict__ WgT,
    const unsigned short* __restrict__ WcT,
    const float* __restrict__ bg,
    const float* __restrict__ bc,
    float* __restrict__ out,
    unsigned short* __restrict__ hpub,
    unsigned short* __restrict__ rpub,
    int* __restrict__ gflagA,
    int* __restrict__ gflagB)
{
    __shared__ unsigned short sWg[32 * PK];        // 98,816 B
    __shared__ unsigned short sWc[16 * PK];        // 49,408 B
    __shared__ float sPrc[4][2][16][16];           //  8,192 B (r partials, then c)
    __shared__ unsigned short sPu[4][2][16][16];   //  4,096 B (u partials, bf16)
    __shared__ unsigned short stage[8][4][16];     //  1,024 B (per-wave quad stage)
                                                   // total 161,536 B

    const int b    = blockIdx.x;
    const int tid  = threadIdx.x;
    const int wid  = tid >> 6;
    const int lane = tid & 63;
    const int l15  = lane & 15;
    const int lq   = lane >> 4;
    const int ks   = wid >> 1;
    const int rt   = wid & 1;
    const int arow = rt * 16 + l15;               // A-fragment load row
    const int bcol0= b * 16;
    const int finm = ks * 4 + (lane >> 4);        // finalize row within rt tile
    const int finrow = rt * 16 + finm;            // finalize batch row
    const int fincol = bcol0 + l15;               // finalize column

    // ---- stage weight slices into LDS (once) ----
    {
        s8v* dst = (s8v*)sWg;
        for (int idx = tid; idx < 32 * K8; idx += TPB) {
            int c = idx / K8, k8 = idx % K8;
            int gc = (c < 16) ? (bcol0 + c) : (HH + bcol0 + (c - 16));
            dst[c * PK8 + k8] = ((const s8v*)(WgT + (size_t)gc * KK))[k8];
        }
        s8v* dst2 = (s8v*)sWc;
        for (int idx = tid; idx < 16 * K8; idx += TPB) {
            int c = idx / K8, k8 = idx % K8;
            dst2[c * PK8 + k8] = ((const s8v*)(WcT + (size_t)(bcol0 + c) * KK))[k8];
        }
    }

    const float bgr = bg[fincol];
    const float bgu = bg[HH + fincol];
    const float bcv = bc[fincol];

    const s8v* sWg8 = (const s8v*)sWg;
    const s8v* sWc8 = (const s8v*)sWc;
    const s8v* bwr = sWg8 + l15 * PK8 + lq;          // r-col weights
    const s8v* bwu = sWg8 + (16 + l15) * PK8 + lq;   // u-col weights
    const s8v* bwc = sWc8 + l15 * PK8 + lq;          // cand weights
    const s8v* bwrx = bwr + 16 * ks;                 // x chunks [4ks..4ks+4)
    const s8v* bwux = bwu + 16 * ks;
    const s8v* bwrh = bwr + 64 + 32 * ks;            // h chunks [8ks..8ks+8)
    const s8v* bwuh = bwu + 64 + 32 * ks;
    const s8v* bwcx = bwc + 16 * ks;
    const s8v* bwch = bwc + 64 + 32 * ks;

    float hprev = 0.f;                // h_{t-1}[finrow][fincol] — per-lane scalar

    __syncthreads();

#pragma unroll 1
    for (int t = 0; t < TT; ++t) {
        const s8v* xk = (const s8v*)(Xbf + (size_t)arow * (TT * DD) + (size_t)t * DD) + lq + 16 * ks;
        s8v x0 = xk[0], x1 = xk[4], x2 = xk[8], x3 = xk[12];   // shared by all 3 GEMMs

        // ========== Phase A critical: r-gate only ==========
        f4v ar0 = {0,0,0,0}, ar1 = {0,0,0,0};
        ar0 = MFMA(x0, bwrx[0],  ar0); ar1 = MFMA(x1, bwrx[4],  ar1);
        ar0 = MFMA(x2, bwrx[8],  ar0); ar1 = MFMA(x3, bwrx[12], ar1);
        u4v hb[8];
        if (t > 0) {
            pollq(gflagB, ks * 16, rt, t, lane);     // h_{t-1} from my 16 producer blocks
            const unsigned short* hp = hpub + (size_t)arow * HH + ks * 256 + lq * 8;
#pragma unroll
            for (int j = 0; j < 8; ++j) hb[j] = cload16(hp + (size_t)j * 32);
            WAIT_VM(4);
            ar0 = MFMA(B16(hb[0]), bwrh[0],  ar0); ar1 = MFMA(B16(hb[1]), bwrh[4],  ar1);
            ar0 = MFMA(B16(hb[2]), bwrh[8],  ar0); ar1 = MFMA(B16(hb[3]), bwrh[12], ar1);
            WAIT_VM(0);
            ar0 = MFMA(B16(hb[4]), bwrh[16], ar0); ar1 = MFMA(B16(hb[5]), bwrh[20], ar1);
            ar0 = MFMA(B16(hb[6]), bwrh[24], ar0); ar1 = MFMA(B16(hb[7]), bwrh[28], ar1);
        }
        f4v pr = ar0 + ar1;
#pragma unroll
        for (int i = 0; i < 4; ++i) sPrc[ks][rt][lq * 4 + i][l15] = pr[i];
        __syncthreads();                             // S1: r partials ready

        // distributed r-finalize + rh publish (all 8 waves, 1 value/lane)
        {
            float zr = sPrc[0][rt][finm][l15] + sPrc[1][rt][finm][l15]
                     + sPrc[2][rt][finm][l15] + sPrc[3][rt][finm][l15] + bgr;
            float r = 1.f / (1.f + __expf(-zr));
            __hip_bfloat16 hb16 = __float2bfloat16(r * hprev);
            stage[wid][lane >> 4][l15] = *(unsigned short*)&hb16;
            if (t > 0) {                             // rh_0 == 0, never read
                if (lane < 16) {
                    u2v v = *reinterpret_cast<const u2v*>(&stage[wid][lane >> 2][(lane & 3) * 4]);
                    cstore8(rpub + (size_t)(rt * 16 + ks * 4 + (lane >> 2)) * HH + bcol0 + (lane & 3) * 4, v);
                }
                asm volatile("s_waitcnt vmcnt(0)" ::: "memory");
                if (lane == 0) cstore4(gflagA + b * 8 + rt * 4 + ks, t);
            }
        }

        // ---- slack work: u-gate (full) + candidate x-part ----
        f4v au0 = {0,0,0,0}, au1 = {0,0,0,0};
        au0 = MFMA(x0, bwux[0],  au0); au1 = MFMA(x1, bwux[4],  au1);
        au0 = MFMA(x2, bwux[8],  au0); au1 = MFMA(x3, bwux[12], au1);
        if (t > 0) {
            au0 = MFMA(B16(hb[0]), bwuh[0],  au0); au1 = MFMA(B16(hb[1]), bwuh[4],  au1);
            au0 = MFMA(B16(hb[2]), bwuh[8],  au0); au1 = MFMA(B16(hb[3]), bwuh[12], au1);
            au0 = MFMA(B16(hb[4]), bwuh[16], au0); au1 = MFMA(B16(hb[5]), bwuh[20], au1);
            au0 = MFMA(B16(hb[6]), bwuh[24], au0); au1 = MFMA(B16(hb[7]), bwuh[28], au1);
        }
        f4v pu = au0 + au1;
#pragma unroll
        for (int i = 0; i < 4; ++i) {
            __hip_bfloat16 ub = __float2bfloat16(pu[i]);
            sPu[ks][rt][lq * 4 + i][l15] = *(unsigned short*)&ub;
        }
        f4v c0 = {0,0,0,0}, c1 = {0,0,0,0};
        c0 = MFMA(x0, bwcx[0],  c0); c1 = MFMA(x1, bwcx[4],  c1);
        c0 = MFMA(x2, bwcx[8],  c0); c1 = MFMA(x3, bwcx[12], c1);
        __syncthreads();                             // S1b: u partials ready; r reads done

        // u-finalize (off critical path)
        float ureg;
        {
            float zu = bfu2f(sPu[0][rt][finm][l15]) + bfu2f(sPu[1][rt][finm][l15])
                     + bfu2f(sPu[2][rt][finm][l15]) + bfu2f(sPu[3][rt][finm][l15]) + bgu;
            ureg = 1.f / (1.f + __expf(-zu));
        }

        // ========== Phase B critical: candidate rh-part ==========
        if (t > 0) {
            pollq(gflagA, ks * 16, rt, t, lane);     // rh_t from my 16 producer blocks
            const unsigned short* rp = rpub + (size_t)arow * HH + ks * 256 + lq * 8;
            u4v rb[8];
#pragma unroll
            for (int j = 0; j < 8; ++j) rb[j] = cload16(rp + (size_t)j * 32);
            WAIT_VM(4);
            c0 = MFMA(B16(rb[0]), bwch[0],  c0); c1 = MFMA(B16(rb[1]), bwch[4],  c1);
            c0 = MFMA(B16(rb[2]), bwch[8],  c0); c1 = MFMA(B16(rb[3]), bwch[12], c1);
            WAIT_VM(0);
            c0 = MFMA(B16(rb[4]), bwch[16], c0); c1 = MFMA(B16(rb[5]), bwch[20], c1);
            c0 = MFMA(B16(rb[6]), bwch[24], c0); c1 = MFMA(B16(rb[7]), bwch[28], c1);
        }
        f4v pc = c0 + c1;
#pragma unroll
        for (int i = 0; i < 4; ++i) sPrc[ks][rt][lq * 4 + i][l15] = pc[i];
        __syncthreads();                             // S2: c partials ready

        // distributed h-finalize + h publish (all 8 waves, 1 value/lane)
        {
            float zc = sPrc[0][rt][finm][l15] + sPrc[1][rt][finm][l15]
                     + sPrc[2][rt][finm][l15] + sPrc[3][rt][finm][l15] + bcv;
            float e = __expf(2.f * zc);
            float cv = 1.f - 2.f / (e + 1.f);
            float hn = ureg * hprev + (1.f - ureg) * cv;
            hprev = hn;
            __hip_bfloat16 hb16 = __float2bfloat16(hn);
            stage[wid][lane >> 4][l15] = *(unsigned short*)&hb16;
            if (lane < 16) {
                u2v v = *reinterpret_cast<const u2v*>(&stage[wid][lane >> 2][(lane & 3) * 4]);
                cstore8(hpub + (size_t)(rt * 16 + ks * 4 + (lane >> 2)) * HH + bcol0 + (lane & 3) * 4, v);
            }
            asm volatile("s_waitcnt vmcnt(0)" ::: "memory");
            if (lane == 0) cstore4(gflagB + b * 8 + rt * 4 + ks, t + 1);
            // out store AFTER the flag — off the rendezvous critical path
            out[(size_t)finrow * (TT * HH) + (size_t)t * HH + fincol] = hn;
        }
        __syncthreads();                             // S3: region-reuse guard (c reads done
                                                     //     before next step's r writes)
    }
}

// ---------------------------------------------------------------------------
extern "C" void kernel_launch(void* const* d_in, const int* in_sizes, int n_in,
                              void* d_out, int out_size, void* d_ws, size_t ws_size,
                              hipStream_t stream) {
    const float* X  = (const float*)d_in[0];
    const float* gk = (const float*)d_in[1];
    const float* gb = (const float*)d_in[2];
    const float* ck = (const float*)d_in[3];
    const float* cb = (const float*)d_in[4];
    float* out = (float*)d_out;
    char* ws = (char*)d_ws;
    if (ws_size < OFF_FLG + SZ_FLG) return;

    unsigned short* WgT  = (unsigned short*)(ws + OFF_WGT);
    unsigned short* WcT  = (unsigned short*)(ws + OFF_WCT);
    unsigned short* Xbf  = (unsigned short*)(ws + OFF_XBF);
    unsigned short* hpub = (unsigned short*)(ws + OFF_HPB);
    unsigned short* rpub = (unsigned short*)(ws + OFF_RPB);
    int*            gflagA = (int*)(ws + OFF_FLG);
    int*            gflagB = gflagA + NBLK * 8;

    hipMemsetAsync(gflagA, 0, SZ_FLG, stream);

    dim3 tb(256);
    wtr_kernel<<<dim3(2 * HH / 32, KK / 32), tb, 0, stream>>>(gk, WgT, 2 * HH);
    wtr_kernel<<<dim3(HH / 32, KK / 32), tb, 0, stream>>>(ck, WcT, HH);
    xconv_kernel<<<(BB * TT * DD) / (256 * 4), tb, 0, stream>>>(X, Xbf);

    gru_kernel<<<NBLK, dim3(TPB), 0, stream>>>(Xbf, WgT, WcT, gb, cb, out,
                                               hpub, rpub, gflagA, gflagB);
}